// Round 15
// baseline (397.607 us; speedup 1.0000x reference)
//
#include <hip/hip_runtime.h>
#include <hip/hip_bf16.h>

#define NN 50000
#define DIN 256
#define HC 256   // H*C per direction
#define NH 4     // heads
#define CC 64    // per-head dim
#define NBLK 49  // ceil(NN/1024) chunks per direction
#define CVTBLK 12500  // convert_x blocks in prep_kernel

typedef __attribute__((ext_vector_type(8))) short short8;
typedef __attribute__((ext_vector_type(4))) float f32x4;

__device__ inline unsigned short f2bf(float f) {
  unsigned int u = __builtin_bit_cast(unsigned int, f);
  u = (u + 0x7FFF + ((u >> 16) & 1)) >> 16;  // RTNE, no NaN inputs here
  return (unsigned short)u;
}
__device__ inline float bf2f(unsigned short u) {
  return __builtin_bit_cast(float, ((unsigned int)u) << 16);
}

// ---------------------------------------------------------------------------
// prep: blocks [0,CVTBLK) convert x->xb (bf16, 4/thread); blocks [CVTBLK,..)
// build WbT[n][k] = (n<256 ? W1 : W2)[k][n%256].
// ---------------------------------------------------------------------------
__global__ __launch_bounds__(256) void prep_kernel(
    const float* __restrict__ x, unsigned short* __restrict__ xb,
    const float* __restrict__ W1, const float* __restrict__ W2,
    unsigned short* __restrict__ wbt) {
  int b = blockIdx.x;
  if (b < CVTBLK) {
    int i = (b * 256 + threadIdx.x) * 4;
    float4 v = *(const float4*)&x[i];
    ushort4 o;
    o.x = f2bf(v.x); o.y = f2bf(v.y); o.z = f2bf(v.z); o.w = f2bf(v.w);
    *(ushort4*)&xb[i] = o;
  } else {
    int idx = (b - CVTBLK) * 256 + threadIdx.x;  // 131072
    int n = idx >> 8;
    int k = idx & 255;
    float v = (n < HC) ? W1[k * HC + n] : W2[k * HC + (n - HC)];
    wbt[n * DIN + k] = f2bf(v);
  }
}

// ---------------------------------------------------------------------------
// Fused MFMA GEMM + es/ed epilogue.
// h[50000][512] = xb @ [W1|W2] via WbT; es/ed computed from fp32 acc.
// One block = 128 rows x ALL 512 cols (n-tile loop inside -> A tile stays in
// this XCD's L2 for tiles 2-4; round-12 grid.y=4 re-fetched A 4x from L3).
// Each wave's 64-col span == one (dir, head), so es/ed = 16-lane reduce.
// ---------------------------------------------------------------------------
__global__ __launch_bounds__(256) void gemm_fused_kernel(
    const unsigned short* __restrict__ xb,
    const unsigned short* __restrict__ wbt, const float* __restrict__ as1,
    const float* __restrict__ ad1, const float* __restrict__ as2,
    const float* __restrict__ ad2, unsigned short* __restrict__ h,
    float* __restrict__ es1, float* __restrict__ ed1,
    float* __restrict__ es2, float* __restrict__ ed2) {
  const int tid = threadIdx.x;
  const int lane = tid & 63;
  const int wid = tid >> 6;
  const int wr = wid >> 1;  // 0..1
  const int wc = wid & 1;   // 0..1
  const int m0 = blockIdx.x * 128 + wr * 64;
  const int fr = lane & 15;
  const int kbase = (lane >> 4) * 8;
  const short8 zero8 = {0, 0, 0, 0, 0, 0, 0, 0};

  int arow[4];
  bool rowok[4];
#pragma unroll
  for (int m = 0; m < 4; ++m) {
    arow[m] = m0 + m * 16 + fr;
    rowok[m] = arow[m] < NN;
  }

  for (int nt = 0; nt < 4; ++nt) {
    const int n0 = nt * 128 + wc * 64;
    f32x4 acc[4][4];
#pragma unroll
    for (int m = 0; m < 4; ++m)
#pragma unroll
      for (int n = 0; n < 4; ++n) acc[m][n] = (f32x4){0.f, 0.f, 0.f, 0.f};

#pragma unroll
    for (int k0 = 0; k0 < DIN; k0 += 32) {
      short8 a[4], b[4];
#pragma unroll
      for (int m = 0; m < 4; ++m)
        a[m] = rowok[m]
                   ? *(const short8*)&xb[(size_t)arow[m] * DIN + k0 + kbase]
                   : zero8;
#pragma unroll
      for (int n = 0; n < 4; ++n)
        b[n] =
            *(const short8*)&wbt[(size_t)(n0 + n * 16 + fr) * DIN + k0 + kbase];
#pragma unroll
      for (int m = 0; m < 4; ++m)
#pragma unroll
        for (int n = 0; n < 4; ++n)
          acc[m][n] = __builtin_amdgcn_mfma_f32_16x16x32_bf16(
              a[m], b[n], acc[m][n], 0, 0, 0);
    }

    // h store. C/D layout: col = lane&15, row = (lane>>4)*4 + j [m89]
#pragma unroll
    for (int m = 0; m < 4; ++m) {
#pragma unroll
      for (int j = 0; j < 4; ++j) {
        int r = m0 + m * 16 + (lane >> 4) * 4 + j;
        if (r < NN) {
#pragma unroll
          for (int n = 0; n < 4; ++n)
            h[(size_t)r * 512 + n0 + n * 16 + fr] = f2bf(acc[m][n][j]);
        }
      }
    }

    // es/ed epilogue: this wave's 64 cols = head hd of direction dir.
    int dir = n0 >> 8;
    int hd = (n0 & 255) >> 6;
    const float* asv = dir ? as2 : as1;
    const float* adv = dir ? ad2 : ad1;
    float* esp = dir ? es2 : es1;
    float* edp = dir ? ed2 : ed1;
    float avs[4], avd[4];
#pragma unroll
    for (int n = 0; n < 4; ++n) {
      int c = n * 16 + fr;
      avs[n] = asv[hd * CC + c];
      avd[n] = adv[hd * CC + c];
    }
#pragma unroll
    for (int m = 0; m < 4; ++m) {
#pragma unroll
      for (int j = 0; j < 4; ++j) {
        float vs = 0.f, vd = 0.f;
#pragma unroll
        for (int n = 0; n < 4; ++n) {
          vs += acc[m][n][j] * avs[n];
          vd += acc[m][n][j] * avd[n];
        }
#pragma unroll
        for (int o = 1; o < 16; o <<= 1) {
          vs += __shfl_xor(vs, o);
          vd += __shfl_xor(vd, o);
        }
        int r = m0 + m * 16 + (lane >> 4) * 4 + j;
        if (fr == 0 && r < NN) {
          esp[r * NH + hd] = vs;
          edp[r * NH + hd] = vd;
        }
      }
    }
  }
}

// ---------------------------------------------------------------------------
// CSR build: degree -> hierarchical scan (3 small kernels) -> fill
// ---------------------------------------------------------------------------
__global__ __launch_bounds__(256) void degree_kernel(
    const int* __restrict__ ei0, const int* __restrict__ ei1,
    int* __restrict__ deg1, int* __restrict__ deg2, int E) {
  int e = blockIdx.x * 256 + threadIdx.x;
  if (e < E) {
    atomicAdd(&deg1[ei1[e]], 1);
    atomicAdd(&deg2[ei0[e]], 1);
  }
}

// stage 1: per-1024-chunk sums. grid = 2*NBLK blocks of 256.
__global__ __launch_bounds__(256) void bsum_kernel(
    const int* __restrict__ deg1, const int* __restrict__ deg2,
    int* __restrict__ bsum) {
  int b = blockIdx.x;  // 0..2*NBLK-1
  int dir = (b >= NBLK);
  int cb = dir ? b - NBLK : b;
  const int* deg = dir ? deg2 : deg1;
  int t = threadIdx.x;
  int base = cb * 1024 + t * 4;
  int s = 0;
#pragma unroll
  for (int k = 0; k < 4; ++k) {
    int i = base + k;
    if (i < NN) s += deg[i];
  }
#pragma unroll
  for (int o = 32; o; o >>= 1) s += __shfl_down(s, o);
  __shared__ int ws[4];
  int lane = t & 63, w = t >> 6;
  if (lane == 0) ws[w] = s;
  __syncthreads();
  if (t == 0) bsum[b] = ws[0] + ws[1] + ws[2] + ws[3];
}

// stage 2: exclusive scan of NBLK chunk sums per dir. 1 block, 2 waves.
__global__ __launch_bounds__(128) void bscan_kernel(int* __restrict__ bsum) {
  int t = threadIdx.x;  // 0..127
  int w = t >> 6, lane = t & 63;
  int idx = w * NBLK + lane;
  int v = (lane < NBLK) ? bsum[idx] : 0;
  int x = v;
#pragma unroll
  for (int o = 1; o < 64; o <<= 1) {
    int y = __shfl_up(x, o);
    if (lane >= o) x += y;
  }
  if (lane < NBLK) bsum[idx] = x - v;  // exclusive
}

// stage 3: write off/cur. same geometry as stage 1.
__global__ __launch_bounds__(256) void offsets_kernel(
    const int* __restrict__ deg1, const int* __restrict__ deg2,
    const int* __restrict__ bsum, int* __restrict__ off1,
    int* __restrict__ cur1, int* __restrict__ off2, int* __restrict__ cur2,
    int E) {
  int b = blockIdx.x;
  int dir = (b >= NBLK);
  int cb = dir ? b - NBLK : b;
  const int* deg = dir ? deg2 : deg1;
  int* off = dir ? off2 : off1;
  int* cur = dir ? cur2 : cur1;
  int t = threadIdx.x;
  int base = cb * 1024 + t * 4;
  int d[4];
  int s = 0;
#pragma unroll
  for (int k = 0; k < 4; ++k) {
    int i = base + k;
    d[k] = (i < NN) ? deg[i] : 0;
    s += d[k];
  }
  int lane = t & 63, w = t >> 6;
  int x = s;
#pragma unroll
  for (int o = 1; o < 64; o <<= 1) {
    int y = __shfl_up(x, o);
    if (lane >= o) x += y;
  }
  __shared__ int ws[4];
  if (lane == 63) ws[w] = x;
  __syncthreads();
  int woff = 0;
  for (int i = 0; i < w; ++i) woff += ws[i];
  int excl = bsum[b] + woff + (x - s);
#pragma unroll
  for (int k = 0; k < 4; ++k) {
    int i = base + k;
    if (i < NN) {
      off[i] = excl;
      cur[i] = excl;
      excl += d[k];
    }
  }
  if (b == 0 && t == 0) {  // both CSRs have exactly E entries
    off1[NN] = E;
    off2[NN] = E;
  }
}

__global__ __launch_bounds__(256) void fill_kernel(
    const int* __restrict__ ei0, const int* __restrict__ ei1,
    int* __restrict__ cur1, int* __restrict__ cur2, int* __restrict__ csr1,
    int* __restrict__ csr2, int E) {
  int e = blockIdx.x * 256 + threadIdx.x;
  if (e < E) {
    int s = ei0[e], d = ei1[e];
    csr1[atomicAdd(&cur1[d], 1)] = s;
    csr2[atomicAdd(&cur2[s], 1)] = d;
  }
}

// ---------------------------------------------------------------------------
// Fused gather: one wave per node, all 4 heads, both directions (sequential
// per-direction loops — round-13 interleave A/B showed no gain; BW-bound).
// ---------------------------------------------------------------------------
__device__ inline void gat_side(int n, int lane, int hd,
                                const unsigned short* __restrict__ h, int half,
                                const float* __restrict__ es,
                                const float* __restrict__ ed,
                                const int* __restrict__ off,
                                const int* __restrict__ csr, float4& res) {
  float edn = ed[n * NH + hd];
  float e0 = es[n * NH + hd] + edn;
  e0 = e0 >= 0.f ? e0 : 0.2f * e0;
  float w0 = __expf(e0);
  size_t hoff = (size_t)half * HC + lane * 4;
  ushort4 hv = *(const ushort4*)&h[(size_t)n * 512 + hoff];
  float wsum = w0;
  float ax = w0 * bf2f(hv.x), ay = w0 * bf2f(hv.y);
  float az = w0 * bf2f(hv.z), aw = w0 * bf2f(hv.w);
  int beg = off[n], end = off[n + 1];
  for (int j = beg; j < end; ++j) {
    int s = csr[j];
    float el = es[s * NH + hd] + edn;
    el = el >= 0.f ? el : 0.2f * el;
    float wg = __expf(el);
    wsum += wg;
    ushort4 sv = *(const ushort4*)&h[(size_t)s * 512 + hoff];
    ax += wg * bf2f(sv.x);
    ay += wg * bf2f(sv.y);
    az += wg * bf2f(sv.z);
    aw += wg * bf2f(sv.w);
  }
  float inv = 1.f / wsum;
  res.x = ax * inv; res.y = ay * inv; res.z = az * inv; res.w = aw * inv;
}

__global__ __launch_bounds__(256) void gather_kernel(
    const unsigned short* __restrict__ h, const float* __restrict__ es1,
    const float* __restrict__ ed1, const float* __restrict__ es2,
    const float* __restrict__ ed2, const float* __restrict__ b1,
    const float* __restrict__ b2, const int* __restrict__ off1,
    const int* __restrict__ csr1, const int* __restrict__ off2,
    const int* __restrict__ csr2, float* __restrict__ out) {
  int n = blockIdx.x * 4 + (threadIdx.x >> 6);  // NN = 12500*4 exactly
  int lane = threadIdx.x & 63;
  int hd = lane >> 4;
  float4 r1, r2;
  gat_side(n, lane, hd, h, 0, es1, ed1, off1, csr1, r1);
  gat_side(n, lane, hd, h, 1, es2, ed2, off2, csr2, r2);
  float4 bv1 = *(const float4*)&b1[lane * 4];
  float4 bv2 = *(const float4*)&b2[lane * 4];
  float4 o;
  o.x = 0.5f * (r1.x + bv1.x + r2.x + bv2.x);
  o.y = 0.5f * (r1.y + bv1.y + r2.y + bv2.y);
  o.z = 0.5f * (r1.z + bv1.z + r2.z + bv2.z);
  o.w = 0.5f * (r1.w + bv1.w + r2.w + bv2.w);
  *(float4*)&out[(size_t)n * HC + lane * 4] = o;
}

// ---------------------------------------------------------------------------
extern "C" void kernel_launch(void* const* d_in, const int* in_sizes, int n_in,
                              void* d_out, int out_size, void* d_ws,
                              size_t ws_size, hipStream_t stream) {
  const float* x = (const float*)d_in[0];
  const int* ei = (const int*)d_in[1];
  const int E = in_sizes[1] / 2;
  const float* W1 = (const float*)d_in[2];
  const float* as1 = (const float*)d_in[3];
  const float* ad1 = (const float*)d_in[4];
  const float* b1 = (const float*)d_in[5];
  const float* W2 = (const float*)d_in[6];
  const float* as2 = (const float*)d_in[7];
  const float* ad2 = (const float*)d_in[8];
  const float* b2 = (const float*)d_in[9];
  float* out = (float*)d_out;
  const int* ei0 = ei;
  const int* ei1 = ei + E;

  // workspace layout
  unsigned short* xb = (unsigned short*)d_ws;       // N*256 bf16
  unsigned short* h = xb + (size_t)NN * DIN;        // N*512 bf16
  unsigned short* wbt = h + (size_t)NN * 512;       // 512*256 bf16
  float* es1 = (float*)(wbt + 512 * DIN);           // N*4 each
  float* ed1 = es1 + NN * NH;
  float* es2 = ed1 + NN * NH;
  float* ed2 = es2 + NN * NH;
  int* deg1 = (int*)(ed2 + NN * NH);
  int* deg2 = deg1 + NN;
  int* off1 = deg2 + NN;
  int* off2 = off1 + (NN + 1);
  int* cur1 = off2 + (NN + 1);
  int* cur2 = cur1 + NN;
  int* csr1 = cur2 + NN;
  int* csr2 = csr1 + E;
  int* bsum = csr2 + E;  // 2*NBLK ints

  hipMemsetAsync(deg1, 0, 2 * NN * sizeof(int), stream);

  prep_kernel<<<CVTBLK + 512, 256, 0, stream>>>(x, xb, W1, W2, wbt);
  degree_kernel<<<(E + 255) / 256, 256, 0, stream>>>(ei0, ei1, deg1, deg2, E);

  gemm_fused_kernel<<<(NN + 127) / 128, 256, 0, stream>>>(
      xb, wbt, as1, ad1, as2, ad2, h, es1, ed1, es2, ed2);

  bsum_kernel<<<2 * NBLK, 256, 0, stream>>>(deg1, deg2, bsum);
  bscan_kernel<<<1, 128, 0, stream>>>(bsum);
  offsets_kernel<<<2 * NBLK, 256, 0, stream>>>(deg1, deg2, bsum, off1, cur1,
                                               off2, cur2, E);
  fill_kernel<<<(E + 255) / 256, 256, 0, stream>>>(ei0, ei1, cur1, cur2, csr1,
                                                   csr2, E);

  gather_kernel<<<NN / 4, 256, 0, stream>>>(h, es1, ed1, es2, ed2, b1, b2,
                                            off1, csr1, off2, csr2, out);
}

// Round 19
// 387.752 us; speedup vs baseline: 1.0254x; 1.0254x over previous
//
#include <hip/hip_runtime.h>
#include <hip/hip_bf16.h>

#define NN 50000
#define DIN 256
#define HC 256   // H*C per direction
#define NH 4     // heads
#define CC 64    // per-head dim
#define NBLK 49  // ceil(NN/1024) chunks per direction

typedef __attribute__((ext_vector_type(8))) short short8;
typedef __attribute__((ext_vector_type(4))) float f32x4;

__device__ inline unsigned short f2bf(float f) {
  unsigned int u = __builtin_bit_cast(unsigned int, f);
  u = (u + 0x7FFF + ((u >> 16) & 1)) >> 16;  // RTNE, no NaN inputs here
  return (unsigned short)u;
}
__device__ inline float bf2f(unsigned short u) {
  return __builtin_bit_cast(float, ((unsigned int)u) << 16);
}

// ---------------------------------------------------------------------------
// x (fp32) -> xb (bf16). 12.8M elements, 4 per thread.
// ---------------------------------------------------------------------------
__global__ __launch_bounds__(256) void convert_x_kernel(
    const float* __restrict__ x, unsigned short* __restrict__ xb) {
  int i = (blockIdx.x * 256 + threadIdx.x) * 4;
  float4 v = *(const float4*)&x[i];
  ushort4 o;
  o.x = f2bf(v.x); o.y = f2bf(v.y); o.z = f2bf(v.z); o.w = f2bf(v.w);
  *(ushort4*)&xb[i] = o;
}

// ---------------------------------------------------------------------------
// WbT[n][k] = (n<256 ? W1 : W2)[k][n%256], bf16. 512x256 elements.
// ---------------------------------------------------------------------------
__global__ __launch_bounds__(256) void wbt_kernel(
    const float* __restrict__ W1, const float* __restrict__ W2,
    unsigned short* __restrict__ wbt) {
  int idx = blockIdx.x * 256 + threadIdx.x;  // 131072
  int n = idx >> 8;
  int k = idx & 255;
  float v = (n < HC) ? W1[k * HC + n] : W2[k * HC + (n - HC)];
  wbt[n * DIN + k] = f2bf(v);
}

// ---------------------------------------------------------------------------
// wproj[col][k], col = dir*8 + typ*4 + hd:  Σ_c W[k][hd*64+c] * a[hd][c]
// ---------------------------------------------------------------------------
__global__ __launch_bounds__(256) void wproj_kernel(
    const float* __restrict__ W1, const float* __restrict__ as1,
    const float* __restrict__ ad1, const float* __restrict__ W2,
    const float* __restrict__ as2, const float* __restrict__ ad2,
    unsigned short* __restrict__ wproj) {
  int idx = blockIdx.x * 256 + threadIdx.x;  // 4096
  int col = idx >> 8;
  int k = idx & 255;
  int dir = col >> 3, typ = (col >> 2) & 1, hd = col & 3;
  const float* W = dir ? W2 : W1;
  const float* a = dir ? (typ ? ad2 : as2) : (typ ? ad1 : as1);
  float s = 0.f;
#pragma unroll 8
  for (int c = 0; c < CC; ++c) s += W[k * HC + hd * CC + c] * a[hd * CC + c];
  wproj[col * DIN + k] = f2bf(s);
}

// ---------------------------------------------------------------------------
// MFMA GEMM: h[50000][512] (bf16) = xb[50000][256] @ [W1|W2] via WbT.
// 128x128 block tile, 4 waves (2x2). grid (391, 4) — measured config (r13).
// ---------------------------------------------------------------------------
__global__ __launch_bounds__(256) void gemm_mfma_kernel(
    const unsigned short* __restrict__ xb,
    const unsigned short* __restrict__ wbt, unsigned short* __restrict__ h) {
  const int tid = threadIdx.x;
  const int lane = tid & 63;
  const int wid = tid >> 6;
  const int wr = wid >> 1;  // 0..1
  const int wc = wid & 1;   // 0..1
  const int m0 = blockIdx.x * 128 + wr * 64;
  const int n0 = blockIdx.y * 128 + wc * 64;
  const int fr = lane & 15;
  const int kbase = (lane >> 4) * 8;

  f32x4 acc[4][4];
#pragma unroll
  for (int m = 0; m < 4; ++m)
#pragma unroll
    for (int n = 0; n < 4; ++n) acc[m][n] = (f32x4){0.f, 0.f, 0.f, 0.f};

  int arow[4];
  bool rowok[4];
#pragma unroll
  for (int m = 0; m < 4; ++m) {
    arow[m] = m0 + m * 16 + fr;
    rowok[m] = arow[m] < NN;
  }
  const short8 zero8 = {0, 0, 0, 0, 0, 0, 0, 0};

  for (int k0 = 0; k0 < DIN; k0 += 32) {
    short8 a[4], b[4];
#pragma unroll
    for (int m = 0; m < 4; ++m)
      a[m] = rowok[m] ? *(const short8*)&xb[(size_t)arow[m] * DIN + k0 + kbase]
                      : zero8;
#pragma unroll
    for (int n = 0; n < 4; ++n)
      b[n] = *(const short8*)&wbt[(size_t)(n0 + n * 16 + fr) * DIN + k0 + kbase];
#pragma unroll
    for (int m = 0; m < 4; ++m)
#pragma unroll
      for (int n = 0; n < 4; ++n)
        acc[m][n] = __builtin_amdgcn_mfma_f32_16x16x32_bf16(a[m], b[n],
                                                            acc[m][n], 0, 0, 0);
  }

  // C/D layout: col = lane&15, row = (lane>>4)*4 + j  [m89-verified]
#pragma unroll
  for (int m = 0; m < 4; ++m) {
#pragma unroll
    for (int j = 0; j < 4; ++j) {
      int r = m0 + m * 16 + (lane >> 4) * 4 + j;
      if (r < NN) {
#pragma unroll
        for (int n = 0; n < 4; ++n) {
          h[(size_t)r * 512 + n0 + n * 16 + fr] = f2bf(acc[m][n][j]);
        }
      }
    }
  }
}

// ---------------------------------------------------------------------------
// Skinny MFMA GEMM: es_ed[n][16] = xb[n][256] @ wproj^T. One wave per 16 rows.
// ---------------------------------------------------------------------------
__global__ __launch_bounds__(256) void esed_gemm_kernel(
    const unsigned short* __restrict__ xb,
    const unsigned short* __restrict__ wproj, float* __restrict__ es1,
    float* __restrict__ ed1, float* __restrict__ es2,
    float* __restrict__ ed2) {
  int wv = blockIdx.x * 4 + (threadIdx.x >> 6);  // 3128 waves
  int lane = threadIdx.x & 63;
  int m0 = wv * 16;
  if (m0 >= NN) return;
  const int fr = lane & 15;
  const int kbase = (lane >> 4) * 8;
  const short8 zero8 = {0, 0, 0, 0, 0, 0, 0, 0};
  f32x4 acc = (f32x4){0.f, 0.f, 0.f, 0.f};
  int arow = m0 + fr;
  bool ok = arow < NN;
#pragma unroll
  for (int k0 = 0; k0 < DIN; k0 += 32) {
    short8 a = ok ? *(const short8*)&xb[(size_t)arow * DIN + k0 + kbase] : zero8;
    short8 b = *(const short8*)&wproj[(size_t)fr * DIN + k0 + kbase];
    acc = __builtin_amdgcn_mfma_f32_16x16x32_bf16(a, b, acc, 0, 0, 0);
  }
  int col = fr;
  int dir = col >> 3, typ = (col >> 2) & 1, hd = col & 3;
  float* dst = dir ? (typ ? ed2 : es2) : (typ ? ed1 : es1);
#pragma unroll
  for (int j = 0; j < 4; ++j) {
    int r = m0 + (lane >> 4) * 4 + j;
    if (r < NN) dst[r * NH + hd] = acc[j];
  }
}

// ---------------------------------------------------------------------------
// CSR build: degree -> hierarchical scan -> fill
// ---------------------------------------------------------------------------
__global__ __launch_bounds__(256) void degree_kernel(
    const int* __restrict__ ei0, const int* __restrict__ ei1,
    int* __restrict__ deg1, int* __restrict__ deg2, int E) {
  int e = blockIdx.x * 256 + threadIdx.x;
  if (e < E) {
    atomicAdd(&deg1[ei1[e]], 1);
    atomicAdd(&deg2[ei0[e]], 1);
  }
}

__global__ __launch_bounds__(256) void bsum_kernel(
    const int* __restrict__ deg1, const int* __restrict__ deg2,
    int* __restrict__ bsum) {
  int b = blockIdx.x;  // 0..2*NBLK-1
  int dir = (b >= NBLK);
  int cb = dir ? b - NBLK : b;
  const int* deg = dir ? deg2 : deg1;
  int t = threadIdx.x;
  int base = cb * 1024 + t * 4;
  int s = 0;
#pragma unroll
  for (int k = 0; k < 4; ++k) {
    int i = base + k;
    if (i < NN) s += deg[i];
  }
#pragma unroll
  for (int o = 32; o; o >>= 1) s += __shfl_down(s, o);
  __shared__ int ws[4];
  int lane = t & 63, w = t >> 6;
  if (lane == 0) ws[w] = s;
  __syncthreads();
  if (t == 0) bsum[b] = ws[0] + ws[1] + ws[2] + ws[3];
}

__global__ __launch_bounds__(128) void bscan_kernel(int* __restrict__ bsum) {
  int t = threadIdx.x;  // 0..127
  int w = t >> 6, lane = t & 63;
  int idx = w * NBLK + lane;
  int v = (lane < NBLK) ? bsum[idx] : 0;
  int x = v;
#pragma unroll
  for (int o = 1; o < 64; o <<= 1) {
    int y = __shfl_up(x, o);
    if (lane >= o) x += y;
  }
  if (lane < NBLK) bsum[idx] = x - v;  // exclusive
}

__global__ __launch_bounds__(256) void offsets_kernel(
    const int* __restrict__ deg1, const int* __restrict__ deg2,
    const int* __restrict__ bsum, int* __restrict__ off1,
    int* __restrict__ cur1, int* __restrict__ off2, int* __restrict__ cur2,
    int E) {
  int b = blockIdx.x;
  int dir = (b >= NBLK);
  int cb = dir ? b - NBLK : b;
  const int* deg = dir ? deg2 : deg1;
  int* off = dir ? off2 : off1;
  int* cur = dir ? cur2 : cur1;
  int t = threadIdx.x;
  int base = cb * 1024 + t * 4;
  int d[4];
  int s = 0;
#pragma unroll
  for (int k = 0; k < 4; ++k) {
    int i = base + k;
    d[k] = (i < NN) ? deg[i] : 0;
    s += d[k];
  }
  int lane = t & 63, w = t >> 6;
  int x = s;
#pragma unroll
  for (int o = 1; o < 64; o <<= 1) {
    int y = __shfl_up(x, o);
    if (lane >= o) x += y;
  }
  __shared__ int ws[4];
  if (lane == 63) ws[w] = x;
  __syncthreads();
  int woff = 0;
  for (int i = 0; i < w; ++i) woff += ws[i];
  int excl = bsum[b] + woff + (x - s);
#pragma unroll
  for (int k = 0; k < 4; ++k) {
    int i = base + k;
    if (i < NN) {
      off[i] = excl;
      cur[i] = excl;
      excl += d[k];
    }
  }
  if (b == 0 && t == 0) {
    off1[NN] = E;
    off2[NN] = E;
  }
}

__global__ __launch_bounds__(256) void fill_kernel(
    const int* __restrict__ ei0, const int* __restrict__ ei1,
    int* __restrict__ cur1, int* __restrict__ cur2, int* __restrict__ csr1,
    int* __restrict__ csr2, int E) {
  int e = blockIdx.x * 256 + threadIdx.x;
  if (e < E) {
    int s = ei0[e], d = ei1[e];
    csr1[atomicAdd(&cur1[d], 1)] = s;
    csr2[atomicAdd(&cur2[s], 1)] = d;
  }
}

// ---------------------------------------------------------------------------
// Gather, direction-split: block = 2 nodes x 2 waves; each wave runs ONE
// direction's edge loop for its node (halves the serial miss chain, doubles
// wave count vs r13). dir-1 wave deposits result in LDS; dir-0 wave combines
// with biases and writes out.
// ---------------------------------------------------------------------------
__global__ __launch_bounds__(256) void gather_kernel(
    const unsigned short* __restrict__ h, const float* __restrict__ es1,
    const float* __restrict__ ed1, const float* __restrict__ es2,
    const float* __restrict__ ed2, const float* __restrict__ b1,
    const float* __restrict__ b2, const int* __restrict__ off1,
    const int* __restrict__ csr1, const int* __restrict__ off2,
    const int* __restrict__ csr2, float* __restrict__ out) {
  int w = threadIdx.x >> 6;
  int lane = threadIdx.x & 63;
  int slot = w >> 1;                       // node slot in block (0,1)
  int n = blockIdx.x * 2 + slot;           // NN = 25000*2 exactly
  int dir = w & 1;
  int hd = lane >> 4;

  const float* es = dir ? es2 : es1;
  const float* ed = dir ? ed2 : ed1;
  const int* off = dir ? off2 : off1;
  const int* csr = dir ? csr2 : csr1;

  float edn = ed[n * NH + hd];
  float e0 = es[n * NH + hd] + edn;
  e0 = e0 >= 0.f ? e0 : 0.2f * e0;
  float w0 = __expf(e0);
  size_t hoff = (size_t)dir * HC + lane * 4;
  ushort4 hv = *(const ushort4*)&h[(size_t)n * 512 + hoff];
  float wsum = w0;
  float ax = w0 * bf2f(hv.x), ay = w0 * bf2f(hv.y);
  float az = w0 * bf2f(hv.z), aw = w0 * bf2f(hv.w);
  int beg = off[n], end = off[n + 1];
  for (int j = beg; j < end; ++j) {
    int s = csr[j];
    float el = es[s * NH + hd] + edn;
    el = el >= 0.f ? el : 0.2f * el;
    float wg = __expf(el);
    wsum += wg;
    ushort4 sv = *(const ushort4*)&h[(size_t)s * 512 + hoff];
    ax += wg * bf2f(sv.x);
    ay += wg * bf2f(sv.y);
    az += wg * bf2f(sv.z);
    aw += wg * bf2f(sv.w);
  }
  float inv = 1.f / wsum;
  float4 r;
  r.x = ax * inv; r.y = ay * inv; r.z = az * inv; r.w = aw * inv;

  __shared__ float comb[2][256];
  if (dir == 1) *(float4*)&comb[slot][lane * 4] = r;
  __syncthreads();
  if (dir == 0) {
    float4 r2 = *(const float4*)&comb[slot][lane * 4];
    float4 bv1 = *(const float4*)&b1[lane * 4];
    float4 bv2 = *(const float4*)&b2[lane * 4];
    float4 o;
    o.x = 0.5f * (r.x + bv1.x + r2.x + bv2.x);
    o.y = 0.5f * (r.y + bv1.y + r2.y + bv2.y);
    o.z = 0.5f * (r.z + bv1.z + r2.z + bv2.z);
    o.w = 0.5f * (r.w + bv1.w + r2.w + bv2.w);
    *(float4*)&out[(size_t)n * HC + lane * 4] = o;
  }
}

// ---------------------------------------------------------------------------
extern "C" void kernel_launch(void* const* d_in, const int* in_sizes, int n_in,
                              void* d_out, int out_size, void* d_ws,
                              size_t ws_size, hipStream_t stream) {
  const float* x = (const float*)d_in[0];
  const int* ei = (const int*)d_in[1];
  const int E = in_sizes[1] / 2;
  const float* W1 = (const float*)d_in[2];
  const float* as1 = (const float*)d_in[3];
  const float* ad1 = (const float*)d_in[4];
  const float* b1 = (const float*)d_in[5];
  const float* W2 = (const float*)d_in[6];
  const float* as2 = (const float*)d_in[7];
  const float* ad2 = (const float*)d_in[8];
  const float* b2 = (const float*)d_in[9];
  float* out = (float*)d_out;
  const int* ei0 = ei;
  const int* ei1 = ei + E;

  // workspace layout
  unsigned short* xb = (unsigned short*)d_ws;       // N*256 bf16
  unsigned short* h = xb + (size_t)NN * DIN;        // N*512 bf16
  unsigned short* wbt = h + (size_t)NN * 512;       // 512*256 bf16
  unsigned short* wproj = wbt + 512 * DIN;          // 16*256 bf16
  float* es1 = (float*)(wproj + 16 * DIN);          // N*4 each
  float* ed1 = es1 + NN * NH;
  float* es2 = ed1 + NN * NH;
  float* ed2 = es2 + NN * NH;
  int* deg1 = (int*)(ed2 + NN * NH);
  int* deg2 = deg1 + NN;
  int* off1 = deg2 + NN;
  int* off2 = off1 + (NN + 1);
  int* cur1 = off2 + (NN + 1);
  int* cur2 = cur1 + NN;
  int* csr1 = cur2 + NN;
  int* csr2 = csr1 + E;
  int* bsum = csr2 + E;  // 2*NBLK ints

  hipMemsetAsync(deg1, 0, 2 * NN * sizeof(int), stream);

  convert_x_kernel<<<NN * DIN / 1024, 256, 0, stream>>>(x, xb);
  wbt_kernel<<<512, 256, 0, stream>>>(W1, W2, wbt);
  wproj_kernel<<<16, 256, 0, stream>>>(W1, as1, ad1, W2, as2, ad2, wproj);
  degree_kernel<<<(E + 255) / 256, 256, 0, stream>>>(ei0, ei1, deg1, deg2, E);

  dim3 ggrid((NN + 127) / 128, 4);
  gemm_mfma_kernel<<<ggrid, 256, 0, stream>>>(xb, wbt, h);
  esed_gemm_kernel<<<(NN / 16 + 3) / 4, 256, 0, stream>>>(xb, wproj, es1, ed1,
                                                          es2, ed2);

  bsum_kernel<<<2 * NBLK, 256, 0, stream>>>(deg1, deg2, bsum);
  bscan_kernel<<<1, 128, 0, stream>>>(bsum);
  offsets_kernel<<<2 * NBLK, 256, 0, stream>>>(deg1, deg2, bsum, off1, cur1,
                                               off2, cur2, E);
  fill_kernel<<<(E + 255) / 256, 256, 0, stream>>>(ei0, ei1, cur1, cur2, csr1,
                                                   csr2, E);

  gather_kernel<<<NN / 2, 256, 0, stream>>>(h, es1, ed1, es2, ed2, b1, b2,
                                            off1, csr1, off2, csr2, out);
}